// Round 1
// baseline (3169.092 us; speedup 1.0000x reference)
//
#include <hip/hip_runtime.h>
#include <math.h>

#define NN 100000
#define DD 128
#define EE 1600000
#define ET (EE + NN)
#define ND (NN * DD)

static __device__ __forceinline__ float lrelu(float v) { return v > 0.f ? v : 0.2f * v; }
static __device__ __forceinline__ float gelu_exact(float v) {
  return 0.5f * v * (1.f + erff(v * 0.7071067811865476f));
}

// ---------------- CSR build ----------------

__global__ void k_zero_int(int* __restrict__ p, int n) {
  int i = blockIdx.x * blockDim.x + threadIdx.x;
  if (i < n) p[i] = 0;
}

__global__ void k_count(const int* __restrict__ ei, int* __restrict__ deg) {
  int t = blockIdx.x * blockDim.x + threadIdx.x;
  if (t >= ET) return;
  int dst = (t < EE) ? ei[EE + t] : (t - EE);
  atomicAdd(&deg[dst], 1);
}

#define SCAN_T 256
#define SCAN_E 2048  // 8 per thread

__global__ void k_scan1(const int* __restrict__ deg, int* __restrict__ bsum) {
  __shared__ int sh[SCAN_T];
  int t = threadIdx.x;
  int base = blockIdx.x * SCAN_E + t * 8;
  int s = 0;
#pragma unroll
  for (int j = 0; j < 8; ++j) { int idx = base + j; if (idx < NN) s += deg[idx]; }
  sh[t] = s; __syncthreads();
  for (int off = SCAN_T / 2; off > 0; off >>= 1) {
    if (t < off) sh[t] += sh[t + off];
    __syncthreads();
  }
  if (t == 0) bsum[blockIdx.x] = sh[0];
}

__global__ void k_scan2(int* __restrict__ bsum, int nb, int* __restrict__ row_ptr) {
  if (threadIdx.x == 0) {
    int run = 0;
    for (int i = 0; i < nb; ++i) { int v = bsum[i]; bsum[i] = run; run += v; }
    row_ptr[NN] = run;
  }
}

__global__ void k_scan3(const int* __restrict__ deg, const int* __restrict__ bsum,
                        int* __restrict__ row_ptr) {
  __shared__ int tmp[SCAN_T];
  int t = threadIdx.x;
  int base = blockIdx.x * SCAN_E + t * 8;
  int loc[8]; int s = 0;
#pragma unroll
  for (int j = 0; j < 8; ++j) {
    loc[j] = s;
    int idx = base + j;
    int v = (idx < NN) ? deg[idx] : 0;
    s += v;
  }
  tmp[t] = s; __syncthreads();
  for (int off = 1; off < SCAN_T; off <<= 1) {
    int v = (t >= off) ? tmp[t - off] : 0;
    __syncthreads();
    tmp[t] += v;
    __syncthreads();
  }
  int excl = tmp[t] - s + bsum[blockIdx.x];
#pragma unroll
  for (int j = 0; j < 8; ++j) { int idx = base + j; if (idx < NN) row_ptr[idx] = excl + loc[j]; }
}

__global__ void k_copy_int(const int* __restrict__ a, int* __restrict__ b, int n) {
  int i = blockIdx.x * blockDim.x + threadIdx.x;
  if (i < n) b[i] = a[i];
}

__global__ void k_scatter(const int* __restrict__ ei, int* __restrict__ cursor,
                          int* __restrict__ csr_src) {
  int t = blockIdx.x * blockDim.x + threadIdx.x;
  if (t >= ET) return;
  int src, dst;
  if (t < EE) { src = ei[t]; dst = ei[EE + t]; } else { src = t - EE; dst = src; }
  int pos = atomicAdd(&cursor[dst], 1);
  csr_src[pos] = src;
}

// ---------------- GEMM: C[M,128] = A[M,128] @ W[128,128] (+bias (+min 10)) ----------------
// mode 0: plain, 1: +bias, 2: +bias then min(.,10)

__global__ __launch_bounds__(256) void k_gemm(const float* __restrict__ A,
                                              const float* __restrict__ W,
                                              const float* __restrict__ bias,
                                              float* __restrict__ C, int M, int mode) {
  __shared__ float sW[64 * 128];  // 32 KB: K-chunk of W
  __shared__ float sA[32 * 64];   // 8 KB: 32 rows x 64 k
  int t = threadIdx.x;
  int row0 = blockIdx.x * 32;
  int rg = t >> 5;          // 0..7 -> row group of 4
  int cg = (t & 31) << 2;   // col base 0..124
  float acc[4][4] = {{0.f}};

  for (int k0 = 0; k0 < 128; k0 += 64) {
    {
      const float4* src = (const float4*)(W + (size_t)k0 * 128);
      float4* dst = (float4*)sW;
      for (int i = t; i < 64 * 32; i += 256) dst[i] = src[i];
    }
    for (int i = t; i < 32 * 16; i += 256) {
      int r = i >> 4, c4 = i & 15;
      int row = row0 + r;
      float4 v = {0.f, 0.f, 0.f, 0.f};
      if (row < M) v = *(const float4*)(A + (size_t)row * 128 + k0 + c4 * 4);
      *(float4*)&sA[r * 64 + c4 * 4] = v;
    }
    __syncthreads();
#pragma unroll
    for (int kk = 0; kk < 64; ++kk) {
      float4 bv = *(const float4*)&sW[kk * 128 + cg];
#pragma unroll
      for (int r = 0; r < 4; ++r) {
        float a = sA[(rg * 4 + r) * 64 + kk];
        acc[r][0] += a * bv.x;
        acc[r][1] += a * bv.y;
        acc[r][2] += a * bv.z;
        acc[r][3] += a * bv.w;
      }
    }
    __syncthreads();
  }

  float4 b4 = {0.f, 0.f, 0.f, 0.f};
  if (mode >= 1) b4 = *(const float4*)&bias[cg];
#pragma unroll
  for (int r = 0; r < 4; ++r) {
    int row = row0 + rg * 4 + r;
    if (row >= M) continue;
    float4 o;
    o.x = acc[r][0] + b4.x;
    o.y = acc[r][1] + b4.y;
    o.z = acc[r][2] + b4.z;
    o.w = acc[r][3] + b4.w;
    if (mode == 2) {
      o.x = fminf(o.x, 10.f); o.y = fminf(o.y, 10.f);
      o.z = fminf(o.z, 10.f); o.w = fminf(o.w, 10.f);
    }
    *(float4*)(C + (size_t)row * 128 + cg) = o;
  }
}

// ---------------- GATv2 edge-softmax aggregation (one wave per dst row) ----------------
// h[dst] = gelu( (sum_j exp(e_j - m) * xl[src_j]) / (sum_j exp(e_j - m)) + b )
// e_j = att . leakyrelu(xl[src_j] + xr[dst]);  online softmax, single edge pass.

__global__ __launch_bounds__(256) void k_gat_agg(const float* __restrict__ xl,
                                                 const float* __restrict__ xr,
                                                 const float* __restrict__ att,
                                                 const float* __restrict__ bias,
                                                 const int* __restrict__ row_ptr,
                                                 const int* __restrict__ csr_src,
                                                 float* __restrict__ hout) {
  int gid = blockIdx.x * blockDim.x + threadIdx.x;
  int row = gid >> 6;
  int lane = gid & 63;
  if (row >= NN) return;

  float2 a = *(const float2*)&att[lane * 2];
  float2 xri = *(const float2*)&xr[(size_t)row * 128 + lane * 2];

  float m = -INFINITY, d = 0.f;
  float accx = 0.f, accy = 0.f;
  int p0 = row_ptr[row], p1 = row_ptr[row + 1];
  for (int p = p0; p < p1; ++p) {
    int s = csr_src[p];
    float2 xls = *(const float2*)&xl[(size_t)s * 128 + lane * 2];
    float e = lrelu(xls.x + xri.x) * a.x + lrelu(xls.y + xri.y) * a.y;
#pragma unroll
    for (int off = 32; off > 0; off >>= 1) e += __shfl_xor(e, off);
    float mn = fmaxf(m, e);
    float scale = __expf(m - mn);   // first iter: exp(-inf)=0
    float w = __expf(e - mn);
    d = d * scale + w;
    accx = accx * scale + w * xls.x;
    accy = accy * scale + w * xls.y;
    m = mn;
  }
  float inv = 1.f / d;
  float2 bv = *(const float2*)&bias[lane * 2];
  float h0 = gelu_exact(accx * inv + bv.x);
  float h1 = gelu_exact(accy * inv + bv.y);
  float2 o = {h0, h1};
  *(float2*)&hout[(size_t)row * 128 + lane * 2] = o;
}

// ---------------- VAE reparameterization ----------------

__global__ void k_z(const float* __restrict__ mu, const float* __restrict__ ls,
                    const float* __restrict__ eps, float* __restrict__ z) {
  int i = blockIdx.x * blockDim.x + threadIdx.x;  // over ND/4
  float4 m = ((const float4*)mu)[i];
  float4 l = ((const float4*)ls)[i];
  float4 e = ((const float4*)eps)[i];
  float4 o;
  o.x = m.x + e.x * expf(l.x);
  o.y = m.y + e.y * expf(l.y);
  o.z = m.z + e.z * expf(l.z);
  o.w = m.w + e.w * expf(l.w);
  ((float4*)z)[i] = o;
}

// ---------------- degree head: out[i] = z[i,:] . W_deg + b ----------------

__global__ __launch_bounds__(256) void k_degp(const float* __restrict__ z,
                                              const float* __restrict__ Wd,
                                              const float* __restrict__ bd,
                                              float* __restrict__ outp) {
  int gid = blockIdx.x * blockDim.x + threadIdx.x;
  int row = gid >> 6;
  int lane = gid & 63;
  if (row >= NN) return;
  float2 zz = *(const float2*)&z[(size_t)row * 128 + lane * 2];
  float2 ww = *(const float2*)&Wd[lane * 2];
  float s = zz.x * ww.x + zz.y * ww.y;
#pragma unroll
  for (int off = 32; off > 0; off >>= 1) s += __shfl_xor(s, off);
  if (lane == 0) outp[row] = s + bd[0];
}

// ---------------- host ----------------

static inline char* take(char*& p, size_t bytes) {
  char* r = p;
  p += (bytes + 255) & ~(size_t)255;
  return r;
}

extern "C" void kernel_launch(void* const* d_in, const int* in_sizes, int n_in,
                              void* d_out, int out_size, void* d_ws, size_t ws_size,
                              hipStream_t stream) {
  const float* x      = (const float*)d_in[0];
  const int*   ei     = (const int*)d_in[1];
  const float* eps    = (const float*)d_in[2];
  const float* encWl  = (const float*)d_in[3];
  const float* encWr  = (const float*)d_in[4];
  const float* encAtt = (const float*)d_in[5];
  const float* encB   = (const float*)d_in[6];
  const float* decWl  = (const float*)d_in[7];
  const float* decWr  = (const float*)d_in[8];
  const float* decAtt = (const float*)d_in[9];
  const float* decB   = (const float*)d_in[10];
  const float* W_mu   = (const float*)d_in[11];
  const float* b_mu   = (const float*)d_in[12];
  const float* W_ls   = (const float*)d_in[13];
  const float* b_ls   = (const float*)d_in[14];
  const float* W_out  = (const float*)d_in[15];
  const float* b_out  = (const float*)d_in[16];
  const float* W_deg  = (const float*)d_in[17];
  const float* b_deg  = (const float*)d_in[18];

  float* out    = (float*)d_out;
  float* x_rec  = out;
  float* z      = out + (size_t)ND;
  float* mu     = out + (size_t)2 * ND;
  float* logstd = out + (size_t)3 * ND;
  float* degp   = out + (size_t)4 * ND;

  char* p = (char*)d_ws;
  int* deg     = (int*)take(p, (size_t)NN * 4);
  int* row_ptr = (int*)take(p, (size_t)(NN + 1) * 4);
  int* cursor  = (int*)take(p, (size_t)NN * 4);
  int* bsum    = (int*)take(p, 64 * 4);
  int* csr_src = (int*)take(p, (size_t)ET * 4);
  float* xl    = (float*)take(p, (size_t)ND * 4);
  float* xr    = (float*)take(p, (size_t)ND * 4);
  float* hbuf  = (float*)take(p, (size_t)ND * 4);

  const int nScan = (NN + SCAN_E - 1) / SCAN_E;  // 49
  const int gN    = (NN + 255) / 256;            // 391
  const int gET   = (ET + 255) / 256;            // 6641
  const int gGemm = (NN + 31) / 32;              // 3125
  const int gWave = (NN * 64 + 255) / 256;       // 25000 (wave per row)
  const int gZ    = (ND / 4 + 255) / 256;        // 12500

  // CSR build (per launch; edge_index is an input)
  k_zero_int<<<gN, 256, 0, stream>>>(deg, NN);
  k_count<<<gET, 256, 0, stream>>>(ei, deg);
  k_scan1<<<nScan, SCAN_T, 0, stream>>>(deg, bsum);
  k_scan2<<<1, 64, 0, stream>>>(bsum, nScan, row_ptr);
  k_scan3<<<nScan, SCAN_T, 0, stream>>>(deg, bsum, row_ptr);
  k_copy_int<<<gN, 256, 0, stream>>>(row_ptr, cursor, NN);
  k_scatter<<<gET, 256, 0, stream>>>(ei, cursor, csr_src);

  // encoder
  const float* h = x;
  for (int l = 0; l < 4; ++l) {
    k_gemm<<<gGemm, 256, 0, stream>>>(h, encWl + (size_t)l * DD * DD, nullptr, xl, NN, 0);
    k_gemm<<<gGemm, 256, 0, stream>>>(h, encWr + (size_t)l * DD * DD, nullptr, xr, NN, 0);
    k_gat_agg<<<gWave, 256, 0, stream>>>(xl, xr, encAtt + (size_t)l * DD,
                                         encB + (size_t)l * DD, row_ptr, csr_src, hbuf);
    h = hbuf;
  }

  // VAE heads
  k_gemm<<<gGemm, 256, 0, stream>>>(h, W_mu, b_mu, mu, NN, 1);
  k_gemm<<<gGemm, 256, 0, stream>>>(h, W_ls, b_ls, logstd, NN, 2);
  k_z<<<gZ, 256, 0, stream>>>(mu, logstd, eps, z);

  // decoder
  h = z;
  for (int l = 0; l < 4; ++l) {
    k_gemm<<<gGemm, 256, 0, stream>>>(h, decWl + (size_t)l * DD * DD, nullptr, xl, NN, 0);
    k_gemm<<<gGemm, 256, 0, stream>>>(h, decWr + (size_t)l * DD * DD, nullptr, xr, NN, 0);
    k_gat_agg<<<gWave, 256, 0, stream>>>(xl, xr, decAtt + (size_t)l * DD,
                                         decB + (size_t)l * DD, row_ptr, csr_src, hbuf);
    h = hbuf;
  }

  // outputs
  k_gemm<<<gGemm, 256, 0, stream>>>(h, W_out, b_out, x_rec, NN, 1);
  k_degp<<<gWave, 256, 0, stream>>>(z, W_deg, b_deg, degp);
}

// Round 2
// 2451.651 us; speedup vs baseline: 1.2926x; 1.2926x over previous
//
#include <hip/hip_runtime.h>
#include <math.h>

#define NN 100000
#define DD 128
#define EE 1600000
#define ET (EE + NN)
#define ND (NN * DD)

static __device__ __forceinline__ float lrelu(float v) { return v > 0.f ? v : 0.2f * v; }
static __device__ __forceinline__ float gelu_exact(float v) {
  return 0.5f * v * (1.f + erff(v * 0.7071067811865476f));
}

// ---------------- CSR build ----------------

__global__ void k_zero_int(int* __restrict__ p, int n) {
  int i = blockIdx.x * blockDim.x + threadIdx.x;
  if (i < n) p[i] = 0;
}

__global__ void k_count(const int* __restrict__ ei, int* __restrict__ deg) {
  int t = blockIdx.x * blockDim.x + threadIdx.x;
  if (t >= ET) return;
  int dst = (t < EE) ? ei[EE + t] : (t - EE);
  atomicAdd(&deg[dst], 1);
}

#define SCAN_T 256
#define SCAN_E 2048  // 8 per thread

__global__ void k_scan1(const int* __restrict__ deg, int* __restrict__ bsum) {
  __shared__ int sh[SCAN_T];
  int t = threadIdx.x;
  int base = blockIdx.x * SCAN_E + t * 8;
  int s = 0;
#pragma unroll
  for (int j = 0; j < 8; ++j) { int idx = base + j; if (idx < NN) s += deg[idx]; }
  sh[t] = s; __syncthreads();
  for (int off = SCAN_T / 2; off > 0; off >>= 1) {
    if (t < off) sh[t] += sh[t + off];
    __syncthreads();
  }
  if (t == 0) bsum[blockIdx.x] = sh[0];
}

__global__ void k_scan2(int* __restrict__ bsum, int nb, int* __restrict__ row_ptr) {
  if (threadIdx.x == 0) {
    int run = 0;
    for (int i = 0; i < nb; ++i) { int v = bsum[i]; bsum[i] = run; run += v; }
    row_ptr[NN] = run;
  }
}

__global__ void k_scan3(const int* __restrict__ deg, const int* __restrict__ bsum,
                        int* __restrict__ row_ptr) {
  __shared__ int tmp[SCAN_T];
  int t = threadIdx.x;
  int base = blockIdx.x * SCAN_E + t * 8;
  int loc[8]; int s = 0;
#pragma unroll
  for (int j = 0; j < 8; ++j) {
    loc[j] = s;
    int idx = base + j;
    int v = (idx < NN) ? deg[idx] : 0;
    s += v;
  }
  tmp[t] = s; __syncthreads();
  for (int off = 1; off < SCAN_T; off <<= 1) {
    int v = (t >= off) ? tmp[t - off] : 0;
    __syncthreads();
    tmp[t] += v;
    __syncthreads();
  }
  int excl = tmp[t] - s + bsum[blockIdx.x];
#pragma unroll
  for (int j = 0; j < 8; ++j) { int idx = base + j; if (idx < NN) row_ptr[idx] = excl + loc[j]; }
}

__global__ void k_copy_int(const int* __restrict__ a, int* __restrict__ b, int n) {
  int i = blockIdx.x * blockDim.x + threadIdx.x;
  if (i < n) b[i] = a[i];
}

__global__ void k_scatter(const int* __restrict__ ei, int* __restrict__ cursor,
                          int* __restrict__ csr_src) {
  int t = blockIdx.x * blockDim.x + threadIdx.x;
  if (t >= ET) return;
  int src, dst;
  if (t < EE) { src = ei[t]; dst = ei[EE + t]; } else { src = t - EE; dst = src; }
  int pos = atomicAdd(&cursor[dst], 1);
  csr_src[pos] = src;
}

// ---------------- single GEMM: C[M,128] = A[M,128] @ W[128,128] (+bias) ----------------

__global__ __launch_bounds__(256) void k_gemm(const float* __restrict__ A,
                                              const float* __restrict__ W,
                                              const float* __restrict__ bias,
                                              float* __restrict__ C, int M, int mode) {
  __shared__ float sW[64 * 128];
  __shared__ float sA[32 * 64];
  int t = threadIdx.x;
  int row0 = blockIdx.x * 32;
  int rg = t >> 5;
  int cg = (t & 31) << 2;
  float acc[4][4] = {{0.f}};

  for (int k0 = 0; k0 < 128; k0 += 64) {
    {
      const float4* src = (const float4*)(W + (size_t)k0 * 128);
      float4* dst = (float4*)sW;
      for (int i = t; i < 64 * 32; i += 256) dst[i] = src[i];
    }
    for (int i = t; i < 32 * 16; i += 256) {
      int r = i >> 4, c4 = i & 15;
      int row = row0 + r;
      float4 v = {0.f, 0.f, 0.f, 0.f};
      if (row < M) v = *(const float4*)(A + (size_t)row * 128 + k0 + c4 * 4);
      *(float4*)&sA[r * 64 + c4 * 4] = v;
    }
    __syncthreads();
#pragma unroll
    for (int kk = 0; kk < 64; ++kk) {
      float4 bv = *(const float4*)&sW[kk * 128 + cg];
#pragma unroll
      for (int r = 0; r < 4; ++r) {
        float a = sA[(rg * 4 + r) * 64 + kk];
        acc[r][0] += a * bv.x;
        acc[r][1] += a * bv.y;
        acc[r][2] += a * bv.z;
        acc[r][3] += a * bv.w;
      }
    }
    __syncthreads();
  }

  float4 b4 = {0.f, 0.f, 0.f, 0.f};
  if (mode >= 1) b4 = *(const float4*)&bias[cg];
#pragma unroll
  for (int r = 0; r < 4; ++r) {
    int row = row0 + rg * 4 + r;
    if (row >= M) continue;
    float4 o;
    o.x = acc[r][0] + b4.x;
    o.y = acc[r][1] + b4.y;
    o.z = acc[r][2] + b4.z;
    o.w = acc[r][3] + b4.w;
    *(float4*)(C + (size_t)row * 128 + cg) = o;
  }
}

// ---------------- fused dual GEMM: C1 = A@W1 (+b1), C2 = A@W2 (+b2, min 10) ----------------
// mode 0: no bias (xl/xr). mode 2: bias both, min(C2,10), and if Z: Z = C1 + eps*exp(C2).
// 64 rows/block, transposed-A LDS so inner loop is 4x ds_read_b128 per 64 FMA.

__global__ __launch_bounds__(256) void k_gemm2(const float* __restrict__ A,
                                               const float* __restrict__ W1,
                                               const float* __restrict__ W2,
                                               const float* __restrict__ b1,
                                               const float* __restrict__ b2,
                                               float* __restrict__ C1,
                                               float* __restrict__ C2,
                                               const float* __restrict__ eps,
                                               float* __restrict__ Z,
                                               int M, int mode) {
  __shared__ float sW1[32 * 128];   // 16 KB
  __shared__ float sW2[32 * 128];   // 16 KB
  __shared__ float sAt[32 * 68];    // 8.5 KB, [k][row] transposed, pad 68 for alignment
  int t = threadIdx.x;
  int row0 = blockIdx.x * 64;
  int g = t >> 5;                 // 8 row-groups of 8 rows
  int l4 = (t & 31) << 2;         // col base
  float acc1[8][4] = {{0.f}};
  float acc2[8][4] = {{0.f}};

  for (int k0 = 0; k0 < 128; k0 += 32) {
    {
      const float4* s1 = (const float4*)(W1 + (size_t)k0 * 128);
      const float4* s2 = (const float4*)(W2 + (size_t)k0 * 128);
      float4* d1 = (float4*)sW1;
      float4* d2 = (float4*)sW2;
#pragma unroll
      for (int i = 0; i < 4; ++i) {
        d1[t + i * 256] = s1[t + i * 256];
        d2[t + i * 256] = s2[t + i * 256];
      }
    }
#pragma unroll
    for (int i = 0; i < 2; ++i) {
      int idx = t + i * 256;           // 512 float4 = 64 rows x 8 float4
      int r = idx >> 3, c4 = idx & 7;
      int row = row0 + r;
      float4 v = {0.f, 0.f, 0.f, 0.f};
      if (row < M) v = *(const float4*)(A + (size_t)row * 128 + k0 + c4 * 4);
      sAt[(c4 * 4 + 0) * 68 + r] = v.x;
      sAt[(c4 * 4 + 1) * 68 + r] = v.y;
      sAt[(c4 * 4 + 2) * 68 + r] = v.z;
      sAt[(c4 * 4 + 3) * 68 + r] = v.w;
    }
    __syncthreads();
#pragma unroll 8
    for (int kk = 0; kk < 32; ++kk) {
      float4 w1 = *(const float4*)&sW1[kk * 128 + l4];
      float4 w2 = *(const float4*)&sW2[kk * 128 + l4];
      float4 aL = *(const float4*)&sAt[kk * 68 + g * 8];
      float4 aH = *(const float4*)&sAt[kk * 68 + g * 8 + 4];
      float av[8] = {aL.x, aL.y, aL.z, aL.w, aH.x, aH.y, aH.z, aH.w};
#pragma unroll
      for (int r = 0; r < 8; ++r) {
        acc1[r][0] = fmaf(av[r], w1.x, acc1[r][0]);
        acc1[r][1] = fmaf(av[r], w1.y, acc1[r][1]);
        acc1[r][2] = fmaf(av[r], w1.z, acc1[r][2]);
        acc1[r][3] = fmaf(av[r], w1.w, acc1[r][3]);
        acc2[r][0] = fmaf(av[r], w2.x, acc2[r][0]);
        acc2[r][1] = fmaf(av[r], w2.y, acc2[r][1]);
        acc2[r][2] = fmaf(av[r], w2.z, acc2[r][2]);
        acc2[r][3] = fmaf(av[r], w2.w, acc2[r][3]);
      }
    }
    __syncthreads();
  }

  float4 bv1 = {0.f, 0.f, 0.f, 0.f}, bv2 = {0.f, 0.f, 0.f, 0.f};
  if (mode >= 1) {
    bv1 = *(const float4*)&b1[l4];
    bv2 = *(const float4*)&b2[l4];
  }
#pragma unroll
  for (int r = 0; r < 8; ++r) {
    int row = row0 + g * 8 + r;
    if (row >= M) continue;
    float4 o1, o2;
    o1.x = acc1[r][0] + bv1.x; o1.y = acc1[r][1] + bv1.y;
    o1.z = acc1[r][2] + bv1.z; o1.w = acc1[r][3] + bv1.w;
    o2.x = acc2[r][0] + bv2.x; o2.y = acc2[r][1] + bv2.y;
    o2.z = acc2[r][2] + bv2.z; o2.w = acc2[r][3] + bv2.w;
    if (mode == 2) {
      o2.x = fminf(o2.x, 10.f); o2.y = fminf(o2.y, 10.f);
      o2.z = fminf(o2.z, 10.f); o2.w = fminf(o2.w, 10.f);
    }
    *(float4*)(C1 + (size_t)row * 128 + l4) = o1;
    *(float4*)(C2 + (size_t)row * 128 + l4) = o2;
    if (Z != nullptr) {
      float4 e4 = *(const float4*)(eps + (size_t)row * 128 + l4);
      float4 z4;
      z4.x = o1.x + e4.x * expf(o2.x);
      z4.y = o1.y + e4.y * expf(o2.y);
      z4.z = o1.z + e4.z * expf(o2.z);
      z4.w = o1.w + e4.w * expf(o2.w);
      *(float4*)(Z + (size_t)row * 128 + l4) = z4;
    }
  }
}

// ---------------- GATv2 edge-softmax aggregation (wave/row, 4-edge batches) ----------------

__global__ __launch_bounds__(256) void k_gat_agg(const float* __restrict__ xl,
                                                 const float* __restrict__ xr,
                                                 const float* __restrict__ att,
                                                 const float* __restrict__ bias,
                                                 const int* __restrict__ row_ptr,
                                                 const int* __restrict__ csr_src,
                                                 float* __restrict__ hout) {
  int gid = blockIdx.x * blockDim.x + threadIdx.x;
  int row = gid >> 6;
  int lane = gid & 63;
  if (row >= NN) return;

  float2 a = *(const float2*)&att[lane * 2];
  float2 xri = *(const float2*)&xr[(size_t)row * 128 + lane * 2];

  float m = -INFINITY, d = 0.f;
  float accx = 0.f, accy = 0.f;
  int p0 = row_ptr[row], p1 = row_ptr[row + 1];

  for (int p = p0; p < p1; p += 4) {
    int n = p1 - p;  // >= 1
    int s0 = csr_src[p];
    int s1 = (n > 1) ? csr_src[p + 1] : 0;
    int s2 = (n > 2) ? csr_src[p + 2] : 0;
    int s3 = (n > 3) ? csr_src[p + 3] : 0;
    float2 x0 = *(const float2*)&xl[(size_t)s0 * 128 + lane * 2];
    float2 x1 = *(const float2*)&xl[(size_t)s1 * 128 + lane * 2];
    float2 x2 = *(const float2*)&xl[(size_t)s2 * 128 + lane * 2];
    float2 x3 = *(const float2*)&xl[(size_t)s3 * 128 + lane * 2];

    float e0 = lrelu(x0.x + xri.x) * a.x + lrelu(x0.y + xri.y) * a.y;
    float e1 = lrelu(x1.x + xri.x) * a.x + lrelu(x1.y + xri.y) * a.y;
    float e2 = lrelu(x2.x + xri.x) * a.x + lrelu(x2.y + xri.y) * a.y;
    float e3 = lrelu(x3.x + xri.x) * a.x + lrelu(x3.y + xri.y) * a.y;

#pragma unroll
    for (int off = 32; off > 0; off >>= 1) {
      e0 += __shfl_xor(e0, off);
      e1 += __shfl_xor(e1, off);
      e2 += __shfl_xor(e2, off);
      e3 += __shfl_xor(e3, off);
    }
    if (n <= 1) e1 = -INFINITY;
    if (n <= 2) e2 = -INFINITY;
    if (n <= 3) e3 = -INFINITY;

    float mx = fmaxf(fmaxf(e0, e1), fmaxf(e2, e3));
    float mn = fmaxf(m, mx);
    float scale = __expf(m - mn);  // first batch: exp(-inf)=0
    float w0 = __expf(e0 - mn);
    float w1 = __expf(e1 - mn);
    float w2 = __expf(e2 - mn);
    float w3 = __expf(e3 - mn);
    d = d * scale + ((w0 + w1) + (w2 + w3));
    accx = accx * scale + ((w0 * x0.x + w1 * x1.x) + (w2 * x2.x + w3 * x3.x));
    accy = accy * scale + ((w0 * x0.y + w1 * x1.y) + (w2 * x2.y + w3 * x3.y));
    m = mn;
  }

  float inv = 1.f / d;
  float2 bv = *(const float2*)&bias[lane * 2];
  float h0 = gelu_exact(accx * inv + bv.x);
  float h1 = gelu_exact(accy * inv + bv.y);
  float2 o = {h0, h1};
  *(float2*)&hout[(size_t)row * 128 + lane * 2] = o;
}

// ---------------- degree head: out[i] = z[i,:] . W_deg + b ----------------

__global__ __launch_bounds__(256) void k_degp(const float* __restrict__ z,
                                              const float* __restrict__ Wd,
                                              const float* __restrict__ bd,
                                              float* __restrict__ outp) {
  int gid = blockIdx.x * blockDim.x + threadIdx.x;
  int row = gid >> 6;
  int lane = gid & 63;
  if (row >= NN) return;
  float2 zz = *(const float2*)&z[(size_t)row * 128 + lane * 2];
  float2 ww = *(const float2*)&Wd[lane * 2];
  float s = zz.x * ww.x + zz.y * ww.y;
#pragma unroll
  for (int off = 32; off > 0; off >>= 1) s += __shfl_xor(s, off);
  if (lane == 0) outp[row] = s + bd[0];
}

// ---------------- host ----------------

static inline char* take(char*& p, size_t bytes) {
  char* r = p;
  p += (bytes + 255) & ~(size_t)255;
  return r;
}

extern "C" void kernel_launch(void* const* d_in, const int* in_sizes, int n_in,
                              void* d_out, int out_size, void* d_ws, size_t ws_size,
                              hipStream_t stream) {
  const float* x      = (const float*)d_in[0];
  const int*   ei     = (const int*)d_in[1];
  const float* eps    = (const float*)d_in[2];
  const float* encWl  = (const float*)d_in[3];
  const float* encWr  = (const float*)d_in[4];
  const float* encAtt = (const float*)d_in[5];
  const float* encB   = (const float*)d_in[6];
  const float* decWl  = (const float*)d_in[7];
  const float* decWr  = (const float*)d_in[8];
  const float* decAtt = (const float*)d_in[9];
  const float* decB   = (const float*)d_in[10];
  const float* W_mu   = (const float*)d_in[11];
  const float* b_mu   = (const float*)d_in[12];
  const float* W_ls   = (const float*)d_in[13];
  const float* b_ls   = (const float*)d_in[14];
  const float* W_out  = (const float*)d_in[15];
  const float* b_out  = (const float*)d_in[16];
  const float* W_deg  = (const float*)d_in[17];
  const float* b_deg  = (const float*)d_in[18];

  float* out    = (float*)d_out;
  float* x_rec  = out;
  float* z      = out + (size_t)ND;
  float* mu     = out + (size_t)2 * ND;
  float* logstd = out + (size_t)3 * ND;
  float* degp   = out + (size_t)4 * ND;

  char* p = (char*)d_ws;
  int* deg     = (int*)take(p, (size_t)NN * 4);
  int* row_ptr = (int*)take(p, (size_t)(NN + 1) * 4);
  int* cursor  = (int*)take(p, (size_t)NN * 4);
  int* bsum    = (int*)take(p, 64 * 4);
  int* csr_src = (int*)take(p, (size_t)ET * 4);
  float* xl    = (float*)take(p, (size_t)ND * 4);
  float* xr    = (float*)take(p, (size_t)ND * 4);
  float* hbuf  = (float*)take(p, (size_t)ND * 4);

  const int nScan  = (NN + SCAN_E - 1) / SCAN_E;  // 49
  const int gN     = (NN + 255) / 256;            // 391
  const int gET    = (ET + 255) / 256;            // 6641
  const int gGemm  = (NN + 31) / 32;              // 3125
  const int gGemm2 = (NN + 63) / 64;              // 1563
  const int gWave  = (NN * 64 + 255) / 256;       // 25000 (wave per row)

  // CSR build (per launch; edge_index is an input)
  k_zero_int<<<gN, 256, 0, stream>>>(deg, NN);
  k_count<<<gET, 256, 0, stream>>>(ei, deg);
  k_scan1<<<nScan, SCAN_T, 0, stream>>>(deg, bsum);
  k_scan2<<<1, 64, 0, stream>>>(bsum, nScan, row_ptr);
  k_scan3<<<nScan, SCAN_T, 0, stream>>>(deg, bsum, row_ptr);
  k_copy_int<<<gN, 256, 0, stream>>>(row_ptr, cursor, NN);
  k_scatter<<<gET, 256, 0, stream>>>(ei, cursor, csr_src);

  // encoder
  const float* h = x;
  for (int l = 0; l < 4; ++l) {
    k_gemm2<<<gGemm2, 256, 0, stream>>>(h, encWl + (size_t)l * DD * DD,
                                        encWr + (size_t)l * DD * DD,
                                        nullptr, nullptr, xl, xr, nullptr, nullptr, NN, 0);
    k_gat_agg<<<gWave, 256, 0, stream>>>(xl, xr, encAtt + (size_t)l * DD,
                                         encB + (size_t)l * DD, row_ptr, csr_src, hbuf);
    h = hbuf;
  }

  // VAE heads: mu, logstd, z in one kernel
  k_gemm2<<<gGemm2, 256, 0, stream>>>(h, W_mu, W_ls, b_mu, b_ls, mu, logstd, eps, z, NN, 2);

  // decoder
  h = z;
  for (int l = 0; l < 4; ++l) {
    k_gemm2<<<gGemm2, 256, 0, stream>>>(h, decWl + (size_t)l * DD * DD,
                                        decWr + (size_t)l * DD * DD,
                                        nullptr, nullptr, xl, xr, nullptr, nullptr, NN, 0);
    k_gat_agg<<<gWave, 256, 0, stream>>>(xl, xr, decAtt + (size_t)l * DD,
                                         decB + (size_t)l * DD, row_ptr, csr_src, hbuf);
    h = hbuf;
  }

  // outputs
  k_gemm<<<gGemm, 256, 0, stream>>>(h, W_out, b_out, x_rec, NN, 1);
  k_degp<<<gWave, 256, 0, stream>>>(z, W_deg, b_deg, degp);
}

// Round 3
// 2409.519 us; speedup vs baseline: 1.3152x; 1.0175x over previous
//
#include <hip/hip_runtime.h>
#include <math.h>

#define NN 100000
#define MPAD 100032
#define DD 128
#define EE 1600000
#define ET (EE + NN)
#define ND (NN * DD)

typedef short bf16x8 __attribute__((ext_vector_type(8)));
typedef float f32x4 __attribute__((ext_vector_type(4)));

static __device__ __forceinline__ unsigned short f2bf(float f) {
  unsigned int u = __float_as_uint(f);
  u += 0x7FFFu + ((u >> 16) & 1u);
  return (unsigned short)(u >> 16);
}
static __device__ __forceinline__ float bf2f(unsigned short h) {
  return __uint_as_float(((unsigned int)h) << 16);
}
static __device__ __forceinline__ float gelu_exact(float v) {
  return 0.5f * v * (1.f + erff(v * 0.7071067811865476f));
}

// ---------------- CSR build ----------------

__global__ void k_zero_int(int* __restrict__ p, int n) {
  int i = blockIdx.x * blockDim.x + threadIdx.x;
  if (i < n) p[i] = 0;
}

__global__ void k_count(const int* __restrict__ ei, int* __restrict__ deg) {
  int t = blockIdx.x * blockDim.x + threadIdx.x;
  if (t >= ET) return;
  int dst = (t < EE) ? ei[EE + t] : (t - EE);
  atomicAdd(&deg[dst], 1);
}

#define SCAN_T 256
#define SCAN_E 2048

__global__ void k_scan1(const int* __restrict__ deg, int* __restrict__ bsum) {
  __shared__ int sh[SCAN_T];
  int t = threadIdx.x;
  int base = blockIdx.x * SCAN_E + t * 8;
  int s = 0;
#pragma unroll
  for (int j = 0; j < 8; ++j) { int idx = base + j; if (idx < NN) s += deg[idx]; }
  sh[t] = s; __syncthreads();
  for (int off = SCAN_T / 2; off > 0; off >>= 1) {
    if (t < off) sh[t] += sh[t + off];
    __syncthreads();
  }
  if (t == 0) bsum[blockIdx.x] = sh[0];
}

__global__ void k_scan2(int* __restrict__ bsum, int nb, int* __restrict__ row_ptr) {
  if (threadIdx.x == 0) {
    int run = 0;
    for (int i = 0; i < nb; ++i) { int v = bsum[i]; bsum[i] = run; run += v; }
    row_ptr[NN] = run;
  }
}

__global__ void k_scan3(const int* __restrict__ deg, const int* __restrict__ bsum,
                        int* __restrict__ row_ptr) {
  __shared__ int tmp[SCAN_T];
  int t = threadIdx.x;
  int base = blockIdx.x * SCAN_E + t * 8;
  int loc[8]; int s = 0;
#pragma unroll
  for (int j = 0; j < 8; ++j) {
    loc[j] = s;
    int idx = base + j;
    int v = (idx < NN) ? deg[idx] : 0;
    s += v;
  }
  tmp[t] = s; __syncthreads();
  for (int off = 1; off < SCAN_T; off <<= 1) {
    int v = (t >= off) ? tmp[t - off] : 0;
    __syncthreads();
    tmp[t] += v;
    __syncthreads();
  }
  int excl = tmp[t] - s + bsum[blockIdx.x];
#pragma unroll
  for (int j = 0; j < 8; ++j) { int idx = base + j; if (idx < NN) row_ptr[idx] = excl + loc[j]; }
}

__global__ void k_copy_int(const int* __restrict__ a, int* __restrict__ b, int n) {
  int i = blockIdx.x * blockDim.x + threadIdx.x;
  if (i < n) b[i] = a[i];
}

__global__ void k_scatter(const int* __restrict__ ei, int* __restrict__ cursor,
                          int* __restrict__ csr_src) {
  int t = blockIdx.x * blockDim.x + threadIdx.x;
  if (t >= ET) return;
  int src, dst;
  if (t < EE) { src = ei[t]; dst = ei[EE + t]; } else { src = t - EE; dst = src; }
  int pos = atomicAdd(&cursor[dst], 1);
  csr_src[pos] = src;
}

// ---------------- weight fragment precompute (19 mats of 128x128) ----------------
// frag-major: for (mat, t, c): lane l, j -> W[t*32 + 8*(l>>4) + j][c*16 + (l&15)]
// stored at wf[mat*16384 + ((t*8+c)*64 + l)*8 + j], hi and lo split.

__global__ __launch_bounds__(256) void k_wconv(const float* __restrict__ encWl,
                                               const float* __restrict__ encWr,
                                               const float* __restrict__ decWl,
                                               const float* __restrict__ decWr,
                                               const float* __restrict__ Wmu,
                                               const float* __restrict__ Wls,
                                               const float* __restrict__ Wout,
                                               unsigned short* __restrict__ wfh,
                                               unsigned short* __restrict__ wfl) {
  int wid = (blockIdx.x * 256 + threadIdx.x) >> 6;
  int lane = threadIdx.x & 63;
  if (wid >= 19 * 32) return;
  int mat = wid >> 5;
  int sub = wid & 31;
  const float* W;
  if (mat < 4) W = encWl + (size_t)mat * 16384;
  else if (mat < 8) W = encWr + (size_t)(mat - 4) * 16384;
  else if (mat < 12) W = decWl + (size_t)(mat - 8) * 16384;
  else if (mat < 16) W = decWr + (size_t)(mat - 12) * 16384;
  else if (mat == 16) W = Wmu;
  else if (mat == 17) W = Wls;
  else W = Wout;
  int t = sub >> 3, c = sub & 7;
  int col = c * 16 + (lane & 15);
  int k0 = t * 32 + (lane >> 4) * 8;
  bf16x8 vh, vl;
#pragma unroll
  for (int j = 0; j < 8; ++j) {
    float w = W[(size_t)(k0 + j) * 128 + col];
    unsigned short h = f2bf(w);
    vh[j] = (short)h;
    vl[j] = (short)f2bf(w - bf2f(h));
  }
  size_t base = ((size_t)wid * 64 + lane) * 8;
  *(bf16x8*)(wfh + base) = vh;
  *(bf16x8*)(wfl + base) = vl;
}

// ---------------- x -> bf16 hi/lo stage ----------------

__global__ void k_xconv(const float* __restrict__ x, unsigned short* __restrict__ sh,
                        unsigned short* __restrict__ sl) {
  int i = blockIdx.x * blockDim.x + threadIdx.x;
  if (i >= MPAD * 128 / 8) return;
  size_t base = (size_t)i * 8;
  float v[8];
  if (base < (size_t)ND) {
    float4 f0 = *(const float4*)(x + base);
    float4 f1 = *(const float4*)(x + base + 4);
    v[0] = f0.x; v[1] = f0.y; v[2] = f0.z; v[3] = f0.w;
    v[4] = f1.x; v[5] = f1.y; v[6] = f1.z; v[7] = f1.w;
  } else {
#pragma unroll
    for (int j = 0; j < 8; ++j) v[j] = 0.f;
  }
  bf16x8 vh, vl;
#pragma unroll
  for (int j = 0; j < 8; ++j) {
    unsigned short h = f2bf(v[j]);
    vh[j] = (short)h;
    vl[j] = (short)f2bf(v[j] - bf2f(h));
  }
  *(bf16x8*)(sh + base) = vh;
  *(bf16x8*)(sl + base) = vl;
}

// ---------------- MFMA GEMM: split-bf16, no LDS ----------------
// MODE 0: C1 = A@W1, C2 = A@W2 (no bias) -> gxl, gxr
// MODE 1: mu = A@W1+b1; ls = min(A@W2+b2,10); Z = mu+eps*exp(ls); Zh/Zl = split(Z)
// MODE 2: C1 = A@W1+b1
template <int MODE>
__global__ __launch_bounds__(256) void k_mm(const unsigned short* __restrict__ Ah,
                                            const unsigned short* __restrict__ Al,
                                            const unsigned short* __restrict__ w1h,
                                            const unsigned short* __restrict__ w1l,
                                            const unsigned short* __restrict__ w2h,
                                            const unsigned short* __restrict__ w2l,
                                            const float* __restrict__ b1,
                                            const float* __restrict__ b2,
                                            float* __restrict__ C1,
                                            float* __restrict__ C2,
                                            const float* __restrict__ eps,
                                            float* __restrict__ Z,
                                            unsigned short* Zh,
                                            unsigned short* Zl) {
  int wv = threadIdx.x >> 6, lane = threadIdx.x & 63;
  int row0 = blockIdx.x * 64 + wv * 16;
  int lrow = lane & 15, lk = lane >> 4;
  f32x4 acc1[8], acc2[8];
#pragma unroll
  for (int c = 0; c < 8; ++c) {
    acc1[c] = (f32x4){0.f, 0.f, 0.f, 0.f};
    acc2[c] = (f32x4){0.f, 0.f, 0.f, 0.f};
  }
  const unsigned short* ap = Ah + (size_t)(row0 + lrow) * 128 + lk * 8;
  const unsigned short* alp = Al + (size_t)(row0 + lrow) * 128 + lk * 8;
#pragma unroll
  for (int t = 0; t < 4; ++t) {
    bf16x8 a_h = *(const bf16x8*)(ap + t * 32);
    bf16x8 a_l = *(const bf16x8*)(alp + t * 32);
#pragma unroll
    for (int c = 0; c < 8; ++c) {
      int fo = ((t * 8 + c) * 64 + lane) * 8;
      bf16x8 wh = *(const bf16x8*)(w1h + fo);
      bf16x8 wl = *(const bf16x8*)(w1l + fo);
      acc1[c] = __builtin_amdgcn_mfma_f32_16x16x32_bf16(a_h, wh, acc1[c], 0, 0, 0);
      acc1[c] = __builtin_amdgcn_mfma_f32_16x16x32_bf16(a_l, wh, acc1[c], 0, 0, 0);
      acc1[c] = __builtin_amdgcn_mfma_f32_16x16x32_bf16(a_h, wl, acc1[c], 0, 0, 0);
      if (MODE != 2) {
        bf16x8 wh2 = *(const bf16x8*)(w2h + fo);
        bf16x8 wl2 = *(const bf16x8*)(w2l + fo);
        acc2[c] = __builtin_amdgcn_mfma_f32_16x16x32_bf16(a_h, wh2, acc2[c], 0, 0, 0);
        acc2[c] = __builtin_amdgcn_mfma_f32_16x16x32_bf16(a_l, wh2, acc2[c], 0, 0, 0);
        acc2[c] = __builtin_amdgcn_mfma_f32_16x16x32_bf16(a_h, wl2, acc2[c], 0, 0, 0);
      }
    }
  }
#pragma unroll
  for (int c = 0; c < 8; ++c) {
    int col = c * 16 + lrow;
#pragma unroll
    for (int r = 0; r < 4; ++r) {
      int grow = row0 + lk * 4 + r;
      if (grow >= NN) continue;
      size_t o = (size_t)grow * 128 + col;
      if (MODE == 0) {
        C1[o] = acc1[c][r];
        C2[o] = acc2[c][r];
      } else if (MODE == 1) {
        float v1 = acc1[c][r] + b1[col];
        float v2 = fminf(acc2[c][r] + b2[col], 10.f);
        C1[o] = v1;
        C2[o] = v2;
        float zf = fmaf(eps[o], expf(v2), v1);
        Z[o] = zf;
        unsigned short hz = f2bf(zf);
        Zh[o] = hz;
        Zl[o] = f2bf(zf - bf2f(hz));
      } else {
        C1[o] = acc1[c][r] + b1[col];
      }
    }
  }
}

// ---------------- GATv2 aggregation: wave/row, 4 groups of 16 lanes, 1 edge/group ----------------

__global__ __launch_bounds__(256) void k_gat_agg(const float* __restrict__ gxl,
                                                 const float* __restrict__ gxr,
                                                 const float* __restrict__ att,
                                                 const float* __restrict__ bias,
                                                 const int* __restrict__ row_ptr,
                                                 const int* __restrict__ csr_src,
                                                 unsigned short* __restrict__ sh,
                                                 unsigned short* __restrict__ sl) {
  int gid = blockIdx.x * blockDim.x + threadIdx.x;
  int row = gid >> 6;
  int lane = gid & 63;
  if (row >= NN) return;
  int g = lane >> 4, j = lane & 15;
  int dbase = j * 8;

  float4 a0 = *(const float4*)&att[dbase];
  float4 a1 = *(const float4*)&att[dbase + 4];
  const float* xrp = &gxr[(size_t)row * 128 + dbase];
  float4 r0 = *(const float4*)xrp;
  float4 r1 = *(const float4*)(xrp + 4);

  float m = -INFINITY, d = 0.f;
  float acc[8] = {0.f, 0.f, 0.f, 0.f, 0.f, 0.f, 0.f, 0.f};
  int p0 = row_ptr[row], p1 = row_ptr[row + 1];

  for (int p = p0 + g; p < p1; p += 4) {
    int s = csr_src[p];
    const float* xlp = &gxl[(size_t)s * 128 + dbase];
    float4 v0 = *(const float4*)xlp;
    float4 v1 = *(const float4*)(xlp + 4);

    float t0, e;
    t0 = v0.x + r0.x; t0 = fmaxf(t0, 0.2f * t0); e = t0 * a0.x;
    t0 = v0.y + r0.y; t0 = fmaxf(t0, 0.2f * t0); e = fmaf(t0, a0.y, e);
    t0 = v0.z + r0.z; t0 = fmaxf(t0, 0.2f * t0); e = fmaf(t0, a0.z, e);
    t0 = v0.w + r0.w; t0 = fmaxf(t0, 0.2f * t0); e = fmaf(t0, a0.w, e);
    t0 = v1.x + r1.x; t0 = fmaxf(t0, 0.2f * t0); e = fmaf(t0, a1.x, e);
    t0 = v1.y + r1.y; t0 = fmaxf(t0, 0.2f * t0); e = fmaf(t0, a1.y, e);
    t0 = v1.z + r1.z; t0 = fmaxf(t0, 0.2f * t0); e = fmaf(t0, a1.z, e);
    t0 = v1.w + r1.w; t0 = fmaxf(t0, 0.2f * t0); e = fmaf(t0, a1.w, e);

    e += __shfl_xor(e, 1);
    e += __shfl_xor(e, 2);
    e += __shfl_xor(e, 4);
    e += __shfl_xor(e, 8);

    float mn = fmaxf(m, e);
    float scl = __expf(m - mn);
    float w = __expf(e - mn);
    d = d * scl + w;
    acc[0] = acc[0] * scl + w * v0.x;
    acc[1] = acc[1] * scl + w * v0.y;
    acc[2] = acc[2] * scl + w * v0.z;
    acc[3] = acc[3] * scl + w * v0.w;
    acc[4] = acc[4] * scl + w * v1.x;
    acc[5] = acc[5] * scl + w * v1.y;
    acc[6] = acc[6] * scl + w * v1.z;
    acc[7] = acc[7] * scl + w * v1.w;
    m = mn;
  }

  // merge 4 groups (flash-style)
  float mo = fmaxf(m, __shfl_xor(m, 16));
  mo = fmaxf(mo, __shfl_xor(mo, 32));
  float scl = __expf(m - mo);  // 0 for empty groups (m = -inf)
  d *= scl;
  d += __shfl_xor(d, 16);
  d += __shfl_xor(d, 32);
#pragma unroll
  for (int k = 0; k < 8; ++k) {
    acc[k] *= scl;
    acc[k] += __shfl_xor(acc[k], 16);
    acc[k] += __shfl_xor(acc[k], 32);
  }

  if (g == 0) {
    float inv = 1.f / d;
    float4 b0 = *(const float4*)&bias[dbase];
    float4 b1v = *(const float4*)&bias[dbase + 4];
    float bb[8] = {b0.x, b0.y, b0.z, b0.w, b1v.x, b1v.y, b1v.z, b1v.w};
    bf16x8 vh, vl;
#pragma unroll
    for (int k = 0; k < 8; ++k) {
      float h = gelu_exact(acc[k] * inv + bb[k]);
      unsigned short hi = f2bf(h);
      vh[k] = (short)hi;
      vl[k] = (short)f2bf(h - bf2f(hi));
    }
    *(bf16x8*)(sh + (size_t)row * 128 + dbase) = vh;
    *(bf16x8*)(sl + (size_t)row * 128 + dbase) = vl;
  }
}

// ---------------- degree head ----------------

__global__ __launch_bounds__(256) void k_degp(const float* __restrict__ z,
                                              const float* __restrict__ Wd,
                                              const float* __restrict__ bd,
                                              float* __restrict__ outp) {
  int gid = blockIdx.x * blockDim.x + threadIdx.x;
  int row = gid >> 6;
  int lane = gid & 63;
  if (row >= NN) return;
  float2 zz = *(const float2*)&z[(size_t)row * 128 + lane * 2];
  float2 ww = *(const float2*)&Wd[lane * 2];
  float s = zz.x * ww.x + zz.y * ww.y;
#pragma unroll
  for (int off = 32; off > 0; off >>= 1) s += __shfl_xor(s, off);
  if (lane == 0) outp[row] = s + bd[0];
}

// ---------------- host ----------------

static inline char* take(char*& p, size_t bytes) {
  char* r = p;
  p += (bytes + 255) & ~(size_t)255;
  return r;
}

extern "C" void kernel_launch(void* const* d_in, const int* in_sizes, int n_in,
                              void* d_out, int out_size, void* d_ws, size_t ws_size,
                              hipStream_t stream) {
  const float* x      = (const float*)d_in[0];
  const int*   ei     = (const int*)d_in[1];
  const float* eps    = (const float*)d_in[2];
  const float* encWl  = (const float*)d_in[3];
  const float* encWr  = (const float*)d_in[4];
  const float* encAtt = (const float*)d_in[5];
  const float* encB   = (const float*)d_in[6];
  const float* decWl  = (const float*)d_in[7];
  const float* decWr  = (const float*)d_in[8];
  const float* decAtt = (const float*)d_in[9];
  const float* decB   = (const float*)d_in[10];
  const float* W_mu   = (const float*)d_in[11];
  const float* b_mu   = (const float*)d_in[12];
  const float* W_ls   = (const float*)d_in[13];
  const float* b_ls   = (const float*)d_in[14];
  const float* W_out  = (const float*)d_in[15];
  const float* b_out  = (const float*)d_in[16];
  const float* W_deg  = (const float*)d_in[17];
  const float* b_deg  = (const float*)d_in[18];

  float* out    = (float*)d_out;
  float* x_rec  = out;
  float* z      = out + (size_t)ND;
  float* mu     = out + (size_t)2 * ND;
  float* logstd = out + (size_t)3 * ND;
  float* degp   = out + (size_t)4 * ND;

  char* p = (char*)d_ws;
  int* deg     = (int*)take(p, (size_t)NN * 4);
  int* row_ptr = (int*)take(p, (size_t)(NN + 1) * 4);
  int* cursor  = (int*)take(p, (size_t)NN * 4);
  int* bsum    = (int*)take(p, 64 * 4);
  int* csr_src = (int*)take(p, (size_t)ET * 4);
  float* gxl   = (float*)take(p, (size_t)ND * 4);
  float* gxr   = (float*)take(p, (size_t)ND * 4);
  unsigned short* stgh = (unsigned short*)take(p, (size_t)MPAD * 128 * 2);
  unsigned short* stgl = (unsigned short*)take(p, (size_t)MPAD * 128 * 2);
  unsigned short* wfh  = (unsigned short*)take(p, (size_t)19 * 16384 * 2);
  unsigned short* wfl  = (unsigned short*)take(p, (size_t)19 * 16384 * 2);

  const int nScan = (NN + SCAN_E - 1) / SCAN_E;   // 49
  const int gN    = (NN + 255) / 256;             // 391
  const int gET   = (ET + 255) / 256;             // 6641
  const int gMM   = MPAD / 64;                    // 1563
  const int gWave = (NN * 64 + 255) / 256;        // 25000
  const int gXC   = (MPAD * 128 / 8 + 255) / 256; // 6252

  // CSR build
  k_zero_int<<<gN, 256, 0, stream>>>(deg, NN);
  k_count<<<gET, 256, 0, stream>>>(ei, deg);
  k_scan1<<<nScan, SCAN_T, 0, stream>>>(deg, bsum);
  k_scan2<<<1, 64, 0, stream>>>(bsum, nScan, row_ptr);
  k_scan3<<<nScan, SCAN_T, 0, stream>>>(deg, bsum, row_ptr);
  k_copy_int<<<gN, 256, 0, stream>>>(row_ptr, cursor, NN);
  k_scatter<<<gET, 256, 0, stream>>>(ei, cursor, csr_src);

  // weight frags + x stage
  k_wconv<<<152, 256, 0, stream>>>(encWl, encWr, decWl, decWr, W_mu, W_ls, W_out, wfh, wfl);
  k_xconv<<<gXC, 256, 0, stream>>>(x, stgh, stgl);

  const size_t WM = 16384;
  // encoder
  for (int l = 0; l < 4; ++l) {
    k_mm<0><<<gMM, 256, 0, stream>>>(stgh, stgl,
                                     wfh + (size_t)l * WM, wfl + (size_t)l * WM,
                                     wfh + (size_t)(4 + l) * WM, wfl + (size_t)(4 + l) * WM,
                                     nullptr, nullptr, gxl, gxr, nullptr, nullptr,
                                     nullptr, nullptr);
    k_gat_agg<<<gWave, 256, 0, stream>>>(gxl, gxr, encAtt + (size_t)l * DD,
                                         encB + (size_t)l * DD, row_ptr, csr_src, stgh, stgl);
  }

  // heads: mu, logstd, z (+ bf16 stage of z)
  k_mm<1><<<gMM, 256, 0, stream>>>(stgh, stgl,
                                   wfh + (size_t)16 * WM, wfl + (size_t)16 * WM,
                                   wfh + (size_t)17 * WM, wfl + (size_t)17 * WM,
                                   b_mu, b_ls, mu, logstd, eps, z, stgh, stgl);

  // decoder
  for (int l = 0; l < 4; ++l) {
    k_mm<0><<<gMM, 256, 0, stream>>>(stgh, stgl,
                                     wfh + (size_t)(8 + l) * WM, wfl + (size_t)(8 + l) * WM,
                                     wfh + (size_t)(12 + l) * WM, wfl + (size_t)(12 + l) * WM,
                                     nullptr, nullptr, gxl, gxr, nullptr, nullptr,
                                     nullptr, nullptr);
    k_gat_agg<<<gWave, 256, 0, stream>>>(gxl, gxr, decAtt + (size_t)l * DD,
                                         decB + (size_t)l * DD, row_ptr, csr_src, stgh, stgl);
  }

  // outputs
  k_mm<2><<<gMM, 256, 0, stream>>>(stgh, stgl,
                                   wfh + (size_t)18 * WM, wfl + (size_t)18 * WM,
                                   nullptr, nullptr, b_out, nullptr, x_rec, nullptr,
                                   nullptr, nullptr, nullptr, nullptr);
  k_degp<<<gWave, 256, 0, stream>>>(z, W_deg, b_deg, degp);
}

// Round 5
// 1747.032 us; speedup vs baseline: 1.8140x; 1.3792x over previous
//
#include <hip/hip_runtime.h>
#include <math.h>

#define NN 100000
#define MPAD 100096
#define DD 128
#define EE 1600000
#define ET (EE + NN)
#define ND (NN * DD)

typedef short bf16x8 __attribute__((ext_vector_type(8)));
typedef float f32x4 __attribute__((ext_vector_type(4)));

static __device__ __forceinline__ unsigned short f2bf(float f) {
  unsigned int u = __float_as_uint(f);
  u += 0x7FFFu + ((u >> 16) & 1u);
  return (unsigned short)(u >> 16);
}
static __device__ __forceinline__ float bf2f(unsigned short h) {
  return __uint_as_float(((unsigned int)h) << 16);
}
static __device__ __forceinline__ float gelu_exact(float v) {
  return 0.5f * v * (1.f + erff(v * 0.7071067811865476f));
}

// ---------------- CSR build ----------------

__global__ void k_zero_int(int* __restrict__ p, int n) {
  int i = blockIdx.x * blockDim.x + threadIdx.x;
  if (i < n) p[i] = 0;
}

__global__ void k_count(const int* __restrict__ ei, int* __restrict__ deg) {
  int t = blockIdx.x * blockDim.x + threadIdx.x;
  if (t >= ET) return;
  int dst = (t < EE) ? ei[EE + t] : (t - EE);
  atomicAdd(&deg[dst], 1);
}

#define SCAN_T 256
#define SCAN_E 2048

__global__ void k_scan1(const int* __restrict__ deg, int* __restrict__ bsum) {
  __shared__ int sh[SCAN_T];
  int t = threadIdx.x;
  int base = blockIdx.x * SCAN_E + t * 8;
  int s = 0;
#pragma unroll
  for (int j = 0; j < 8; ++j) { int idx = base + j; if (idx < NN) s += deg[idx]; }
  sh[t] = s; __syncthreads();
  for (int off = SCAN_T / 2; off > 0; off >>= 1) {
    if (t < off) sh[t] += sh[t + off];
    __syncthreads();
  }
  if (t == 0) bsum[blockIdx.x] = sh[0];
}

__global__ void k_scan2(int* __restrict__ bsum, int nb, int* __restrict__ row_ptr) {
  if (threadIdx.x == 0) {
    int run = 0;
    for (int i = 0; i < nb; ++i) { int v = bsum[i]; bsum[i] = run; run += v; }
    row_ptr[NN] = run;
  }
}

__global__ void k_scan3(const int* __restrict__ deg, const int* __restrict__ bsum,
                        int* __restrict__ row_ptr) {
  __shared__ int tmp[SCAN_T];
  int t = threadIdx.x;
  int base = blockIdx.x * SCAN_E + t * 8;
  int loc[8]; int s = 0;
#pragma unroll
  for (int j = 0; j < 8; ++j) {
    loc[j] = s;
    int idx = base + j;
    int v = (idx < NN) ? deg[idx] : 0;
    s += v;
  }
  tmp[t] = s; __syncthreads();
  for (int off = 1; off < SCAN_T; off <<= 1) {
    int v = (t >= off) ? tmp[t - off] : 0;
    __syncthreads();
    tmp[t] += v;
    __syncthreads();
  }
  int excl = tmp[t] - s + bsum[blockIdx.x];
#pragma unroll
  for (int j = 0; j < 8; ++j) { int idx = base + j; if (idx < NN) row_ptr[idx] = excl + loc[j]; }
}

__global__ void k_copy_int(const int* __restrict__ a, int* __restrict__ b, int n) {
  int i = blockIdx.x * blockDim.x + threadIdx.x;
  if (i < n) b[i] = a[i];
}

__global__ void k_scatter(const int* __restrict__ ei, int* __restrict__ cursor,
                          int* __restrict__ csr_src) {
  int t = blockIdx.x * blockDim.x + threadIdx.x;
  if (t >= ET) return;
  int src, dst;
  if (t < EE) { src = ei[t]; dst = ei[EE + t]; } else { src = t - EE; dst = src; }
  int pos = atomicAdd(&cursor[dst], 1);
  csr_src[pos] = src;
}

// ---------------- weight fragment precompute (19 mats of 128x128) ----------------
// frag-major: for (mat, t, c): lane l, j -> W[t*32 + 8*(l>>4) + j][c*16 + (l&15)]
// stored at wf[mat*16384 + ((t*8+c)*64 + l)*8 + j], hi and lo split.

__global__ __launch_bounds__(256) void k_wconv(const float* __restrict__ encWl,
                                               const float* __restrict__ encWr,
                                               const float* __restrict__ decWl,
                                               const float* __restrict__ decWr,
                                               const float* __restrict__ Wmu,
                                               const float* __restrict__ Wls,
                                               const float* __restrict__ Wout,
                                               unsigned short* __restrict__ wfh,
                                               unsigned short* __restrict__ wfl) {
  int wid = (blockIdx.x * 256 + threadIdx.x) >> 6;
  int lane = threadIdx.x & 63;
  if (wid >= 19 * 32) return;
  int mat = wid >> 5;
  int sub = wid & 31;
  const float* W;
  if (mat < 4) W = encWl + (size_t)mat * 16384;
  else if (mat < 8) W = encWr + (size_t)(mat - 4) * 16384;
  else if (mat < 12) W = decWl + (size_t)(mat - 8) * 16384;
  else if (mat < 16) W = decWr + (size_t)(mat - 12) * 16384;
  else if (mat == 16) W = Wmu;
  else if (mat == 17) W = Wls;
  else W = Wout;
  int t = sub >> 3, c = sub & 7;
  int col = c * 16 + (lane & 15);
  int k0 = t * 32 + (lane >> 4) * 8;
  bf16x8 vh, vl;
#pragma unroll
  for (int j = 0; j < 8; ++j) {
    float w = W[(size_t)(k0 + j) * 128 + col];
    unsigned short h = f2bf(w);
    vh[j] = (short)h;
    vl[j] = (short)f2bf(w - bf2f(h));
  }
  size_t base = ((size_t)wid * 64 + lane) * 8;
  *(bf16x8*)(wfh + base) = vh;
  *(bf16x8*)(wfl + base) = vl;
}

// ---------------- x -> bf16 hi/lo stage ----------------

__global__ void k_xconv(const float* __restrict__ x, unsigned short* __restrict__ sh,
                        unsigned short* __restrict__ sl) {
  int i = blockIdx.x * blockDim.x + threadIdx.x;
  if (i >= MPAD * 128 / 8) return;
  size_t base = (size_t)i * 8;
  float v[8];
  if (base < (size_t)ND) {
    float4 f0 = *(const float4*)(x + base);
    float4 f1 = *(const float4*)(x + base + 4);
    v[0] = f0.x; v[1] = f0.y; v[2] = f0.z; v[3] = f0.w;
    v[4] = f1.x; v[5] = f1.y; v[6] = f1.z; v[7] = f1.w;
  } else {
#pragma unroll
    for (int j = 0; j < 8; ++j) v[j] = 0.f;
  }
  bf16x8 vh, vl;
#pragma unroll
  for (int j = 0; j < 8; ++j) {
    unsigned short h = f2bf(v[j]);
    vh[j] = (short)h;
    vl[j] = (short)f2bf(v[j] - bf2f(h));
  }
  *(bf16x8*)(sh + base) = vh;
  *(bf16x8*)(sl + base) = vl;
}

// ---------------- MFMA GEMM: split-bf16, weights staged in LDS ----------------
// 512 threads = 8 waves; block covers 256 rows; each wave: 2 row-tiles of 16.
// MODE 0: C1 = A@W1, C2 = A@W2 (no bias) -> gxl, gxr
// MODE 1: mu = A@W1+b1; ls = min(A@W2+b2,10); Z = mu+eps*exp(ls); Zh/Zl = split(Z)
// MODE 2: C1 = A@W1+b1
template <int MODE>
__global__ __launch_bounds__(512, 2) void k_mm(const unsigned short* __restrict__ Ah,
                                               const unsigned short* __restrict__ Al,
                                               const unsigned short* __restrict__ w1h,
                                               const unsigned short* __restrict__ w1l,
                                               const unsigned short* __restrict__ w2h,
                                               const unsigned short* __restrict__ w2l,
                                               const float* __restrict__ b1,
                                               const float* __restrict__ b2,
                                               float* __restrict__ C1,
                                               float* __restrict__ C2,
                                               const float* __restrict__ eps,
                                               float* __restrict__ Z,
                                               unsigned short* Zh,
                                               unsigned short* Zl) {
  __shared__ unsigned short lw[4 * 16384];  // w1h | w1l | w2h | w2l, 32 KB each
  int tid = threadIdx.x;
  {
    int4* d = (int4*)lw;
    const int4* s1h = (const int4*)w1h;
    const int4* s1l = (const int4*)w1l;
#pragma unroll
    for (int i = 0; i < 4; ++i) {
      d[tid + i * 512] = s1h[tid + i * 512];
      d[2048 + tid + i * 512] = s1l[tid + i * 512];
    }
    if (MODE != 2) {
      const int4* s2h = (const int4*)w2h;
      const int4* s2l = (const int4*)w2l;
#pragma unroll
      for (int i = 0; i < 4; ++i) {
        d[4096 + tid + i * 512] = s2h[tid + i * 512];
        d[6144 + tid + i * 512] = s2l[tid + i * 512];
      }
    }
  }
  __syncthreads();

  int wv = tid >> 6, lane = tid & 63;
  int lrow = lane & 15, lk = lane >> 4;
  int rbase = blockIdx.x * 256 + wv * 32;

  // preload A fragments: 2 tiles x 4 k-steps, hi+lo
  bf16x8 a_h[2][4], a_l[2][4];
#pragma unroll
  for (int n = 0; n < 2; ++n) {
    const unsigned short* ap = Ah + (size_t)(rbase + n * 16 + lrow) * 128 + lk * 8;
    const unsigned short* alp = Al + (size_t)(rbase + n * 16 + lrow) * 128 + lk * 8;
#pragma unroll
    for (int t = 0; t < 4; ++t) {
      a_h[n][t] = *(const bf16x8*)(ap + t * 32);
      a_l[n][t] = *(const bf16x8*)(alp + t * 32);
    }
  }

  f32x4 acc1[2][8], acc2[2][8];
#pragma unroll
  for (int n = 0; n < 2; ++n)
#pragma unroll
    for (int c = 0; c < 8; ++c) {
      acc1[n][c] = (f32x4){0.f, 0.f, 0.f, 0.f};
      acc2[n][c] = (f32x4){0.f, 0.f, 0.f, 0.f};
    }

#pragma unroll
  for (int t = 0; t < 4; ++t) {
#pragma unroll
    for (int c = 0; c < 8; ++c) {
      int fo = ((t * 8 + c) * 64 + lane) * 8;
      bf16x8 wh = *(const bf16x8*)(lw + fo);
      bf16x8 wl = *(const bf16x8*)(lw + 16384 + fo);
#pragma unroll
      for (int n = 0; n < 2; ++n) {
        acc1[n][c] = __builtin_amdgcn_mfma_f32_16x16x32_bf16(a_h[n][t], wh, acc1[n][c], 0, 0, 0);
        acc1[n][c] = __builtin_amdgcn_mfma_f32_16x16x32_bf16(a_l[n][t], wh, acc1[n][c], 0, 0, 0);
        acc1[n][c] = __builtin_amdgcn_mfma_f32_16x16x32_bf16(a_h[n][t], wl, acc1[n][c], 0, 0, 0);
      }
      if (MODE != 2) {
        bf16x8 wh2 = *(const bf16x8*)(lw + 32768 + fo);
        bf16x8 wl2 = *(const bf16x8*)(lw + 49152 + fo);
#pragma unroll
        for (int n = 0; n < 2; ++n) {
          acc2[n][c] = __builtin_amdgcn_mfma_f32_16x16x32_bf16(a_h[n][t], wh2, acc2[n][c], 0, 0, 0);
          acc2[n][c] = __builtin_amdgcn_mfma_f32_16x16x32_bf16(a_l[n][t], wh2, acc2[n][c], 0, 0, 0);
          acc2[n][c] = __builtin_amdgcn_mfma_f32_16x16x32_bf16(a_h[n][t], wl2, acc2[n][c], 0, 0, 0);
        }
      }
    }
  }

#pragma unroll
  for (int n = 0; n < 2; ++n) {
#pragma unroll
    for (int c = 0; c < 8; ++c) {
      int col = c * 16 + lrow;
#pragma unroll
      for (int r = 0; r < 4; ++r) {
        int grow = rbase + n * 16 + lk * 4 + r;
        if (grow >= NN) continue;
        size_t o = (size_t)grow * 128 + col;
        if (MODE == 0) {
          C1[o] = acc1[n][c][r];
          C2[o] = acc2[n][c][r];
        } else if (MODE == 1) {
          float v1 = acc1[n][c][r] + b1[col];
          float v2 = fminf(acc2[n][c][r] + b2[col], 10.f);
          C1[o] = v1;
          C2[o] = v2;
          float zf = fmaf(eps[o], expf(v2), v1);
          Z[o] = zf;
          unsigned short hz = f2bf(zf);
          Zh[o] = hz;
          Zl[o] = f2bf(zf - bf2f(hz));
        } else {
          C1[o] = acc1[n][c][r] + b1[col];
        }
      }
    }
  }
}

// ---------------- GATv2 aggregation: wave/row, 4 groups of 16 lanes, 1 edge/group ----------------

__global__ __launch_bounds__(256) void k_gat_agg(const float* __restrict__ gxl,
                                                 const float* __restrict__ gxr,
                                                 const float* __restrict__ att,
                                                 const float* __restrict__ bias,
                                                 const int* __restrict__ row_ptr,
                                                 const int* __restrict__ csr_src,
                                                 unsigned short* __restrict__ sh,
                                                 unsigned short* __restrict__ sl) {
  int gid = blockIdx.x * blockDim.x + threadIdx.x;
  int row = gid >> 6;
  int lane = gid & 63;
  if (row >= NN) return;
  int g = lane >> 4, j = lane & 15;
  int dbase = j * 8;

  float4 a0 = *(const float4*)&att[dbase];
  float4 a1 = *(const float4*)&att[dbase + 4];
  const float* xrp = &gxr[(size_t)row * 128 + dbase];
  float4 r0 = *(const float4*)xrp;
  float4 r1 = *(const float4*)(xrp + 4);

  float m = -INFINITY, d = 0.f;
  float acc[8] = {0.f, 0.f, 0.f, 0.f, 0.f, 0.f, 0.f, 0.f};
  int p0 = row_ptr[row], p1 = row_ptr[row + 1];

  for (int p = p0 + g; p < p1; p += 4) {
    int s = csr_src[p];
    const float* xlp = &gxl[(size_t)s * 128 + dbase];
    float4 v0 = *(const float4*)xlp;
    float4 v1 = *(const float4*)(xlp + 4);

    float t0, e;
    t0 = v0.x + r0.x; t0 = fmaxf(t0, 0.2f * t0); e = t0 * a0.x;
    t0 = v0.y + r0.y; t0 = fmaxf(t0, 0.2f * t0); e = fmaf(t0, a0.y, e);
    t0 = v0.z + r0.z; t0 = fmaxf(t0, 0.2f * t0); e = fmaf(t0, a0.z, e);
    t0 = v0.w + r0.w; t0 = fmaxf(t0, 0.2f * t0); e = fmaf(t0, a0.w, e);
    t0 = v1.x + r1.x; t0 = fmaxf(t0, 0.2f * t0); e = fmaf(t0, a1.x, e);
    t0 = v1.y + r1.y; t0 = fmaxf(t0, 0.2f * t0); e = fmaf(t0, a1.y, e);
    t0 = v1.z + r1.z; t0 = fmaxf(t0, 0.2f * t0); e = fmaf(t0, a1.z, e);
    t0 = v1.w + r1.w; t0 = fmaxf(t0, 0.2f * t0); e = fmaf(t0, a1.w, e);

    e += __shfl_xor(e, 1);
    e += __shfl_xor(e, 2);
    e += __shfl_xor(e, 4);
    e += __shfl_xor(e, 8);

    float mn = fmaxf(m, e);
    float scl = __expf(m - mn);
    float w = __expf(e - mn);
    d = d * scl + w;
    acc[0] = acc[0] * scl + w * v0.x;
    acc[1] = acc[1] * scl + w * v0.y;
    acc[2] = acc[2] * scl + w * v0.z;
    acc[3] = acc[3] * scl + w * v0.w;
    acc[4] = acc[4] * scl + w * v1.x;
    acc[5] = acc[5] * scl + w * v1.y;
    acc[6] = acc[6] * scl + w * v1.z;
    acc[7] = acc[7] * scl + w * v1.w;
    m = mn;
  }

  // merge 4 groups (flash-style)
  float mo = fmaxf(m, __shfl_xor(m, 16));
  mo = fmaxf(mo, __shfl_xor(mo, 32));
  float scl = __expf(m - mo);  // 0 for empty groups (m = -inf)
  d *= scl;
  d += __shfl_xor(d, 16);
  d += __shfl_xor(d, 32);
#pragma unroll
  for (int k = 0; k < 8; ++k) {
    acc[k] *= scl;
    acc[k] += __shfl_xor(acc[k], 16);
    acc[k] += __shfl_xor(acc[k], 32);
  }

  if (g == 0) {
    float inv = 1.f / d;
    float4 b0 = *(const float4*)&bias[dbase];
    float4 b1v = *(const float4*)&bias[dbase + 4];
    float bb[8] = {b0.x, b0.y, b0.z, b0.w, b1v.x, b1v.y, b1v.z, b1v.w};
    bf16x8 vh, vl;
#pragma unroll
    for (int k = 0; k < 8; ++k) {
      float h = gelu_exact(acc[k] * inv + bb[k]);
      unsigned short hi = f2bf(h);
      vh[k] = (short)hi;
      vl[k] = (short)f2bf(h - bf2f(hi));
    }
    *(bf16x8*)(sh + (size_t)row * 128 + dbase) = vh;
    *(bf16x8*)(sl + (size_t)row * 128 + dbase) = vl;
  }
}

// ---------------- degree head ----------------

__global__ __launch_bounds__(256) void k_degp(const float* __restrict__ z,
                                              const float* __restrict__ Wd,
                                              const float* __restrict__ bd,
                                              float* __restrict__ outp) {
  int gid = blockIdx.x * blockDim.x + threadIdx.x;
  int row = gid >> 6;
  int lane = gid & 63;
  if (row >= NN) return;
  float2 zz = *(const float2*)&z[(size_t)row * 128 + lane * 2];
  float2 ww = *(const float2*)&Wd[lane * 2];
  float s = zz.x * ww.x + zz.y * ww.y;
#pragma unroll
  for (int off = 32; off > 0; off >>= 1) s += __shfl_xor(s, off);
  if (lane == 0) outp[row] = s + bd[0];
}

// ---------------- host ----------------

static inline char* take(char*& p, size_t bytes) {
  char* r = p;
  p += (bytes + 255) & ~(size_t)255;
  return r;
}

extern "C" void kernel_launch(void* const* d_in, const int* in_sizes, int n_in,
                              void* d_out, int out_size, void* d_ws, size_t ws_size,
                              hipStream_t stream) {
  const float* x      = (const float*)d_in[0];
  const int*   ei     = (const int*)d_in[1];
  const float* eps    = (const float*)d_in[2];
  const float* encWl  = (const float*)d_in[3];
  const float* encWr  = (const float*)d_in[4];
  const float* encAtt = (const float*)d_in[5];
  const float* encB   = (const float*)d_in[6];
  const float* decWl  = (const float*)d_in[7];
  const float* decWr  = (const float*)d_in[8];
  const float* decAtt = (const float*)d_in[9];
  const float* decB   = (const float*)d_in[10];
  const float* W_mu   = (const float*)d_in[11];
  const float* b_mu   = (const float*)d_in[12];
  const float* W_ls   = (const float*)d_in[13];
  const float* b_ls   = (const float*)d_in[14];
  const float* W_out  = (const float*)d_in[15];
  const float* b_out  = (const float*)d_in[16];
  const float* W_deg  = (const float*)d_in[17];
  const float* b_deg  = (const float*)d_in[18];

  float* out    = (float*)d_out;
  float* x_rec  = out;
  float* z      = out + (size_t)ND;
  float* mu     = out + (size_t)2 * ND;
  float* logstd = out + (size_t)3 * ND;
  float* degp   = out + (size_t)4 * ND;

  char* p = (char*)d_ws;
  int* deg     = (int*)take(p, (size_t)NN * 4);
  int* row_ptr = (int*)take(p, (size_t)(NN + 1) * 4);
  int* cursor  = (int*)take(p, (size_t)NN * 4);
  int* bsum    = (int*)take(p, 64 * 4);
  int* csr_src = (int*)take(p, (size_t)ET * 4);
  float* gxl   = (float*)take(p, (size_t)ND * 4);
  float* gxr   = (float*)take(p, (size_t)ND * 4);
  unsigned short* stgh = (unsigned short*)take(p, (size_t)MPAD * 128 * 2);
  unsigned short* stgl = (unsigned short*)take(p, (size_t)MPAD * 128 * 2);
  unsigned short* wfh  = (unsigned short*)take(p, (size_t)19 * 16384 * 2);
  unsigned short* wfl  = (unsigned short*)take(p, (size_t)19 * 16384 * 2);

  const int nScan = (NN + SCAN_E - 1) / SCAN_E;   // 49
  const int gN    = (NN + 255) / 256;             // 391
  const int gET   = (ET + 255) / 256;             // 6641
  const int gMM   = MPAD / 256;                   // 391
  const int gWave = (NN * 64 + 255) / 256;        // 25000
  const int gXC   = (MPAD * 128 / 8 + 255) / 256; // 6256

  // CSR build
  k_zero_int<<<gN, 256, 0, stream>>>(deg, NN);
  k_count<<<gET, 256, 0, stream>>>(ei, deg);
  k_scan1<<<nScan, SCAN_T, 0, stream>>>(deg, bsum);
  k_scan2<<<1, 64, 0, stream>>>(bsum, nScan, row_ptr);
  k_scan3<<<nScan, SCAN_T, 0, stream>>>(deg, bsum, row_ptr);
  k_copy_int<<<gN, 256, 0, stream>>>(row_ptr, cursor, NN);
  k_scatter<<<gET, 256, 0, stream>>>(ei, cursor, csr_src);

  // weight frags + x stage
  k_wconv<<<152, 256, 0, stream>>>(encWl, encWr, decWl, decWr, W_mu, W_ls, W_out, wfh, wfl);
  k_xconv<<<gXC, 256, 0, stream>>>(x, stgh, stgl);

  const size_t WM = 16384;
  // encoder
  for (int l = 0; l < 4; ++l) {
    k_mm<0><<<gMM, 512, 0, stream>>>(stgh, stgl,
                                     wfh + (size_t)l * WM, wfl + (size_t)l * WM,
                                     wfh + (size_t)(4 + l) * WM, wfl + (size_t)(4 + l) * WM,
                                     nullptr, nullptr, gxl, gxr, nullptr, nullptr,
                                     nullptr, nullptr);
    k_gat_agg<<<gWave, 256, 0, stream>>>(gxl, gxr, encAtt + (size_t)l * DD,
                                         encB + (size_t)l * DD, row_ptr, csr_src, stgh, stgl);
  }

  // heads: mu, logstd, z (+ bf16 stage of z)
  k_mm<1><<<gMM, 512, 0, stream>>>(stgh, stgl,
                                   wfh + (size_t)16 * WM, wfl + (size_t)16 * WM,
                                   wfh + (size_t)17 * WM, wfl + (size_t)17 * WM,
                                   b_mu, b_ls, mu, logstd, eps, z, stgh, stgl);

  // decoder
  for (int l = 0; l < 4; ++l) {
    k_mm<0><<<gMM, 512, 0, stream>>>(stgh, stgl,
                                     wfh + (size_t)(8 + l) * WM, wfl + (size_t)(8 + l) * WM,
                                     wfh + (size_t)(12 + l) * WM, wfl + (size_t)(12 + l) * WM,
                                     nullptr, nullptr, gxl, gxr, nullptr, nullptr,
                                     nullptr, nullptr);
    k_gat_agg<<<gWave, 256, 0, stream>>>(gxl, gxr, decAtt + (size_t)l * DD,
                                         decB + (size_t)l * DD, row_ptr, csr_src, stgh, stgl);
  }

  // outputs
  k_mm<2><<<gMM, 512, 0, stream>>>(stgh, stgl,
                                   wfh + (size_t)18 * WM, wfl + (size_t)18 * WM,
                                   nullptr, nullptr, b_out, nullptr,
                                   x_rec, nullptr, nullptr, nullptr, nullptr, nullptr);
  k_degp<<<gWave, 256, 0, stream>>>(z, W_deg, b_deg, degp);
}